// Round 1
// baseline (691.194 us; speedup 1.0000x reference)
//
#include <hip/hip_runtime.h>
#include <hip/hip_bf16.h>
#include <hip/hip_fp16.h>

// SwinV2 window attention, MI355X/gfx950.
// Pipeline: k_cvt_w -> k_cpb -> k_comb -> k_attn (qkv+norm+softmax+PV fused per (b,h)) -> k_proj.
// Workspace requirement: ~134.8 MB (comb fp16 67MB + tables/weights ~0.5MB + O bf16 67MB).

#define LOG100F 4.605170185988091f

typedef __attribute__((ext_vector_type(8))) __bf16 bf16x8;
typedef __attribute__((ext_vector_type(4))) float f32x4;
typedef __attribute__((ext_vector_type(8))) unsigned short u16x8;
typedef __attribute__((ext_vector_type(4))) unsigned short u16x4;

__device__ __forceinline__ unsigned short f2bf(float f) {
  unsigned int u = __float_as_uint(f);
  return (unsigned short)((u + 0x7FFFu + ((u >> 16) & 1u)) >> 16);
}
__device__ __forceinline__ unsigned short f2h(float f) {
  __half hv = __float2half(f);
  return __builtin_bit_cast(unsigned short, hv);
}
__device__ __forceinline__ float h2f(unsigned short b) {
  return __half2float(__builtin_bit_cast(__half, b));
}
__device__ __forceinline__ bf16x8 lds8(const unsigned short* p) {
  u16x8 v = *(const u16x8*)p;
  return __builtin_bit_cast(bf16x8, v);
}
__device__ __forceinline__ f32x4 mfma16(bf16x8 a, bf16x8 b, f32x4 c) {
  return __builtin_amdgcn_mfma_f32_16x16x32_bf16(a, b, c, 0, 0, 0);
}

// ---------------- kernel 1: convert weights to bf16 ----------------
__global__ void k_cvt_w(const float* __restrict__ qkv_w, const float* __restrict__ proj_w,
                        unsigned short* __restrict__ wqkv, unsigned short* __restrict__ wproj) {
  const int t = blockIdx.x * 256 + threadIdx.x;  // grid covers 196608 + 65536
  if (t < 768 * 256) {
    wqkv[t] = f2bf(qkv_w[t]);
  } else {
    const int t2 = t - 768 * 256;
    wproj[t2] = f2bf(proj_w[t2]);
  }
}

// ---------------- kernel 2: CPB MLP -> bias_table[961][8] ----------------
__global__ void k_cpb(const float* __restrict__ w1, const float* __restrict__ b1,
                      const float* __restrict__ w2, float* __restrict__ bt) {
  const int row = blockIdx.x;    // 0..960
  const int lane = threadIdx.x;  // 0..63 (one wave)
  const int i = row / 31, j = row % 31;
  // f(x) = sign(x)*log2(8|x|+1)/3 on x = (idx-15)/15
  float x0 = (i - 15) * (1.0f / 15.0f);
  float x1 = (j - 15) * (1.0f / 15.0f);
  float v0 = log2f(fmaf(8.0f, fabsf(x0), 1.0f)) * (1.0f / 3.0f); v0 = x0 < 0.0f ? -v0 : v0;
  float v1 = log2f(fmaf(8.0f, fabsf(x1), 1.0f)) * (1.0f / 3.0f); v1 = x1 < 0.0f ? -v1 : v1;
  float a[8] = {0.f, 0.f, 0.f, 0.f, 0.f, 0.f, 0.f, 0.f};
  for (int jj = lane; jj < 512; jj += 64) {
    float hv = fmaf(w1[2 * jj], v0, fmaf(w1[2 * jj + 1], v1, b1[jj]));
    hv = fmaxf(hv, 0.0f);
#pragma unroll
    for (int hh = 0; hh < 8; ++hh) a[hh] = fmaf(hv, w2[hh * 512 + jj], a[hh]);
  }
#pragma unroll
  for (int hh = 0; hh < 8; ++hh) {
#pragma unroll
    for (int mm = 1; mm < 64; mm <<= 1) a[hh] += __shfl_xor(a[hh], mm);
  }
  float outv = a[0];
#pragma unroll
  for (int hh = 1; hh < 8; ++hh)
    if (lane == hh) outv = a[hh];
  if (lane < 8) bt[row * 8 + lane] = outv;
}

// ---------------- kernel 3: comb[w][h][m][n] = mask[w][n][m] + 16*sigmoid(bt[idx(n,m)][h]) (fp16) ----------------
__global__ void k_comb(const float* __restrict__ mask, const float* __restrict__ bt,
                       unsigned short* __restrict__ comb) {
  const int t = blockIdx.x * 256 + threadIdx.x;  // 64*8*256*32 = 4194304 threads
  const int n0 = (t & 31) * 8;
  const int m = (t >> 5) & 255;
  const int h = (t >> 13) & 7;
  const int w = t >> 16;
  const int jh = m >> 4, jw = m & 15;
  const float* mb = mask + w * 65536 + m;  // mask[w][n][m], n strided
  u16x8 ov;
#pragma unroll
  for (int e = 0; e < 8; ++e) {
    const int n = n0 + e;
    const int ih = n >> 4, iw = n & 15;
    const int idx = (ih - jh + 15) * 31 + (iw - jw + 15);
    const float bv = bt[idx * 8 + h];
    const float sig = 16.0f / (1.0f + __expf(-bv));
    ov[e] = f2h(mb[n * 256] + sig);
  }
  *(u16x8*)(comb + t * 8) = ov;  // flat == ((w*8+h)*256 + m)*256 + n0
}

// ---------------- kernel 4: fused qkv + cosine attention per (b,h) ----------------
__global__ __launch_bounds__(512, 2) void k_attn(
    const float* __restrict__ x, const float* __restrict__ q_bias,
    const float* __restrict__ v_bias, const float* __restrict__ logit_scale,
    const unsigned short* __restrict__ wqkv, const unsigned short* __restrict__ comb,
    unsigned short* __restrict__ Obuf) {
  __shared__ unsigned short lx[256 * 32];  // x k-slice, bf16, XOR-swizzled
  __shared__ unsigned short lw[96 * 32];   // W_h k-slice [q32|k32|v32][32]
  __shared__ unsigned short lq[256 * 32];  // q-hat (normalized * scale)
  __shared__ unsigned short lk[256 * 32];  // k-hat
  __shared__ unsigned short lv[32 * 256];  // v transposed [d][n]
  __shared__ unsigned short lp[8 * 32 * 32];  // per-wave P staging

  const int bid = blockIdx.x;
  const int g = bid & 7, h = (bid >> 3) & 7, w = bid >> 6;  // g fastest: 8 consecutive blocks share comb plane
  const int b = g * 64 + w;
  const int tid = threadIdx.x;
  const int lane = tid & 63, wid = tid >> 6;
  const int l16 = lane & 15, lg = lane >> 4;

  const float sl = __expf(fminf(logit_scale[h], LOG100F));

  // ---- Phase A: [256 x 96] = x[b] @ W_h^T, K=256 in 8 steps ----
  f32x4 acc[2][6];
#pragma unroll
  for (int i = 0; i < 2; ++i)
#pragma unroll
    for (int j = 0; j < 6; ++j) acc[i][j] = (f32x4){0.f, 0.f, 0.f, 0.f};

  for (int kt = 0; kt < 8; ++kt) {
    const int k0 = kt * 32;
    // stage x slice: 256 rows x 32 cols fp32 -> bf16 (2048 float4 tasks)
#pragma unroll
    for (int it = 0; it < 4; ++it) {
      const int task = it * 512 + tid;
      const int row = task >> 3, c4 = task & 7;
      const float4 vs = *(const float4*)(x + ((b * 256 + row) * 256 + k0 + c4 * 4));
      const int chunk = (c4 >> 1) ^ (row & 3);
      u16x4 pk;
      pk.x = f2bf(vs.x); pk.y = f2bf(vs.y); pk.z = f2bf(vs.z); pk.w = f2bf(vs.w);
      *(u16x4*)(lx + row * 32 + chunk * 8 + (c4 & 1) * 4) = pk;
    }
    // stage W_h slice: rows {q: h*32+r, k: 256+h*32+r, v: 512+h*32+r}
    if (tid < 384) {
      const int row = tid >> 2, c = tid & 3;
      const int sec = row >> 5, rr = row & 31;
      const int grow = sec * 256 + h * 32 + rr;
      u16x8 vv = *(const u16x8*)(wqkv + grow * 256 + k0 + c * 8);
      *(u16x8*)(lw + row * 32 + ((c ^ (row & 3)) << 3)) = vv;
    }
    __syncthreads();
    bf16x8 afr[2];
#pragma unroll
    for (int rf = 0; rf < 2; ++rf) {
      const int n = wid * 32 + rf * 16 + l16;
      afr[rf] = lds8(lx + n * 32 + ((lg ^ (n & 3)) << 3));
    }
#pragma unroll
    for (int cf = 0; cf < 6; ++cf) {
      const int cc = cf * 16 + l16;
      bf16x8 bfr = lds8(lw + cc * 32 + ((lg ^ (cc & 3)) << 3));
#pragma unroll
      for (int rf = 0; rf < 2; ++rf) acc[rf][cf] = mfma16(afr[rf], bfr, acc[rf][cf]);
    }
    __syncthreads();
  }

  // ---- Phase A epilogue: bias, row-normalize q (with scale) and k, write lq/lk/lv ----
  const float qb0 = q_bias[h * 32 + l16], qb1 = q_bias[h * 32 + 16 + l16];
  const float vb0 = v_bias[h * 32 + l16], vb1 = v_bias[h * 32 + 16 + l16];
#pragma unroll
  for (int rf = 0; rf < 2; ++rf) {
#pragma unroll
    for (int r = 0; r < 4; ++r) {
      const int n = wid * 32 + rf * 16 + lg * 4 + r;
      const float q0 = acc[rf][0][r] + qb0, q1 = acc[rf][1][r] + qb1;
      const float k0v = acc[rf][2][r], k1v = acc[rf][3][r];
      const float v0 = acc[rf][4][r] + vb0, v1 = acc[rf][5][r] + vb1;
      float sq = q0 * q0 + q1 * q1;
      sq += __shfl_xor(sq, 1); sq += __shfl_xor(sq, 2);
      sq += __shfl_xor(sq, 4); sq += __shfl_xor(sq, 8);
      float sk = k0v * k0v + k1v * k1v;
      sk += __shfl_xor(sk, 1); sk += __shfl_xor(sk, 2);
      sk += __shfl_xor(sk, 4); sk += __shfl_xor(sk, 8);
      const float rq = sl / fmaxf(sqrtf(sq), 1e-12f);
      const float rk = 1.0f / fmaxf(sqrtf(sk), 1e-12f);
      const int d0 = l16, d1 = 16 + l16;
      lq[n * 32 + ((((d0 >> 3) ^ n) & 3) << 3) + (d0 & 7)] = f2bf(q0 * rq);
      lq[n * 32 + ((((d1 >> 3) ^ n) & 3) << 3) + (d1 & 7)] = f2bf(q1 * rq);
      lk[n * 32 + ((((d0 >> 3) ^ n) & 3) << 3) + (d0 & 7)] = f2bf(k0v * rk);
      lk[n * 32 + ((((d1 >> 3) ^ n) & 3) << 3) + (d1 & 7)] = f2bf(k1v * rk);
      lv[d0 * 256 + ((((n >> 3) ^ d0) & 31) << 3) + (n & 7)] = f2bf(v0);
      lv[d1 * 256 + ((((n >> 3) ^ d1) & 31) << 3) + (n & 7)] = f2bf(v1);
    }
  }
  __syncthreads();

  // ---- Phase B: S = qhat @ khat^T (+bias), softmax, O = P @ V ----
  bf16x8 aq[2];
#pragma unroll
  for (int rf = 0; rf < 2; ++rf) {
    const int n = wid * 32 + rf * 16 + l16;
    aq[rf] = lds8(lq + n * 32 + ((lg ^ (n & 3)) << 3));
  }
  f32x4 s[2][16];
#pragma unroll
  for (int cf = 0; cf < 16; ++cf) {
    const int m = cf * 16 + l16;
    bf16x8 bk = lds8(lk + m * 32 + ((lg ^ (m & 3)) << 3));
#pragma unroll
    for (int rf = 0; rf < 2; ++rf) s[rf][cf] = mfma16(aq[rf], bk, (f32x4){0.f, 0.f, 0.f, 0.f});
  }
  // add combined bias (comb[w][h][m][n], fp16, 4 consecutive n per load)
  const unsigned short* cplane = comb + (w * 8 + h) * 65536;
#pragma unroll
  for (int rf = 0; rf < 2; ++rf) {
    const int nb = wid * 32 + rf * 16 + lg * 4;
#pragma unroll
    for (int cf = 0; cf < 16; ++cf) {
      const int m = cf * 16 + l16;
      u16x4 bb = *(const u16x4*)(cplane + m * 256 + nb);
      s[rf][cf][0] += h2f(bb.x);
      s[rf][cf][1] += h2f(bb.y);
      s[rf][cf][2] += h2f(bb.z);
      s[rf][cf][3] += h2f(bb.w);
    }
  }
  // full-row softmax (row lives across 16 lanes x 16 col-frags)
  float rsum[2][4];
#pragma unroll
  for (int rf = 0; rf < 2; ++rf) {
#pragma unroll
    for (int r = 0; r < 4; ++r) {
      float mx = s[rf][0][r];
#pragma unroll
      for (int cf = 1; cf < 16; ++cf) mx = fmaxf(mx, s[rf][cf][r]);
      mx = fmaxf(mx, __shfl_xor(mx, 1));
      mx = fmaxf(mx, __shfl_xor(mx, 2));
      mx = fmaxf(mx, __shfl_xor(mx, 4));
      mx = fmaxf(mx, __shfl_xor(mx, 8));
      float sm = 0.0f;
#pragma unroll
      for (int cf = 0; cf < 16; ++cf) {
        const float p = __expf(s[rf][cf][r] - mx);
        s[rf][cf][r] = p;
        sm += p;
      }
      sm += __shfl_xor(sm, 1); sm += __shfl_xor(sm, 2);
      sm += __shfl_xor(sm, 4); sm += __shfl_xor(sm, 8);
      rsum[rf][r] = sm;
    }
  }
  // PV: stage P 32-col chunks through per-wave LDS (C-layout -> A-frag transpose)
  f32x4 o[2][2];
#pragma unroll
  for (int i = 0; i < 2; ++i)
#pragma unroll
    for (int j = 0; j < 2; ++j) o[i][j] = (f32x4){0.f, 0.f, 0.f, 0.f};
  unsigned short* psw = lp + wid * 1024;
#pragma unroll
  for (int cc = 0; cc < 8; ++cc) {
#pragma unroll
    for (int rf = 0; rf < 2; ++rf)
#pragma unroll
      for (int q8 = 0; q8 < 2; ++q8) {
        const int cf = cc * 2 + q8;
#pragma unroll
        for (int r = 0; r < 4; ++r) {
          const int lr = rf * 16 + lg * 4 + r;
          const int ml = q8 * 16 + l16;
          psw[lr * 32 + ((((ml >> 3) ^ lr) & 3) << 3) + (ml & 7)] = f2bf(s[rf][cf][r]);
        }
      }
    asm volatile("s_waitcnt lgkmcnt(0)" ::: "memory");
    __builtin_amdgcn_sched_barrier(0);
    bf16x8 pa[2];
#pragma unroll
    for (int rf = 0; rf < 2; ++rf) {
      const int lr = rf * 16 + l16;
      pa[rf] = lds8(psw + lr * 32 + (((lg ^ lr) & 3) << 3));
    }
#pragma unroll
    for (int df = 0; df < 2; ++df) {
      const int d = df * 16 + l16;
      bf16x8 bv = lds8(lv + d * 256 + ((((cc * 4 + lg) ^ d) & 31) << 3));
#pragma unroll
      for (int rf = 0; rf < 2; ++rf) o[rf][df] = mfma16(pa[rf], bv, o[rf][df]);
    }
    __builtin_amdgcn_sched_barrier(0);
  }
  // write O (bf16) to [b][n][h*32+d]
#pragma unroll
  for (int rf = 0; rf < 2; ++rf)
#pragma unroll
    for (int df = 0; df < 2; ++df)
#pragma unroll
      for (int r = 0; r < 4; ++r) {
        const int n = wid * 32 + rf * 16 + lg * 4 + r;
        const int col = h * 32 + df * 16 + l16;
        Obuf[(b * 256 + n) * 256 + col] = f2bf(o[rf][df][r] / rsum[rf][r]);
      }
}

// ---------------- kernel 5: out = O @ proj_w^T + proj_b (fp32 out) ----------------
__global__ __launch_bounds__(256, 2) void k_proj(
    const unsigned short* __restrict__ Obuf, const unsigned short* __restrict__ wproj,
    const float* __restrict__ proj_b, float* __restrict__ out) {
  __shared__ unsigned short la[128 * 32];
  __shared__ unsigned short lb[128 * 32];
  const int rb = blockIdx.x >> 1, cb = blockIdx.x & 1;
  const int tid = threadIdx.x, lane = tid & 63, wid = tid >> 6;
  const int wr = wid >> 1, wc = wid & 1;
  const int l16 = lane & 15, lg = lane >> 4;
  f32x4 acc[4][4];
#pragma unroll
  for (int i = 0; i < 4; ++i)
#pragma unroll
    for (int j = 0; j < 4; ++j) acc[i][j] = (f32x4){0.f, 0.f, 0.f, 0.f};
  for (int kt = 0; kt < 8; ++kt) {
    const int k0 = kt * 32;
#pragma unroll
    for (int it = 0; it < 2; ++it) {
      const int task = it * 256 + tid;
      const int row = task >> 2, c = task & 3;
      u16x8 va = *(const u16x8*)(Obuf + (rb * 128 + row) * 256 + k0 + c * 8);
      *(u16x8*)(la + row * 32 + ((c ^ (row & 3)) << 3)) = va;
      u16x8 vb = *(const u16x8*)(wproj + (cb * 128 + row) * 256 + k0 + c * 8);
      *(u16x8*)(lb + row * 32 + ((c ^ (row & 3)) << 3)) = vb;
    }
    __syncthreads();
    bf16x8 a[4];
#pragma unroll
    for (int af = 0; af < 4; ++af) {
      const int rr = wr * 64 + af * 16 + l16;
      a[af] = lds8(la + rr * 32 + ((lg ^ (rr & 3)) << 3));
    }
#pragma unroll
    for (int cf = 0; cf < 4; ++cf) {
      const int ccc = wc * 64 + cf * 16 + l16;
      bf16x8 bfr = lds8(lb + ccc * 32 + ((lg ^ (ccc & 3)) << 3));
#pragma unroll
      for (int af = 0; af < 4; ++af) acc[af][cf] = mfma16(a[af], bfr, acc[af][cf]);
    }
    __syncthreads();
  }
#pragma unroll
  for (int cf = 0; cf < 4; ++cf) {
    const int col = cb * 128 + wc * 64 + cf * 16 + l16;
    const float pb = proj_b[col];
#pragma unroll
    for (int af = 0; af < 4; ++af)
#pragma unroll
      for (int r = 0; r < 4; ++r) {
        const int row = rb * 128 + wr * 64 + af * 16 + lg * 4 + r;
        out[row * 256 + col] = acc[af][cf][r] + pb;
      }
  }
}

extern "C" void kernel_launch(void* const* d_in, const int* in_sizes, int n_in,
                              void* d_out, int out_size, void* d_ws, size_t ws_size,
                              hipStream_t stream) {
  (void)in_sizes; (void)n_in; (void)out_size; (void)ws_size;
  const float* x = (const float*)d_in[0];
  const float* mask = (const float*)d_in[1];
  const float* qkv_w = (const float*)d_in[2];
  const float* q_bias = (const float*)d_in[3];
  const float* v_bias = (const float*)d_in[4];
  const float* logit_scale = (const float*)d_in[5];
  const float* cpb_w1 = (const float*)d_in[6];
  const float* cpb_b1 = (const float*)d_in[7];
  const float* cpb_w2 = (const float*)d_in[8];
  const float* proj_w = (const float*)d_in[9];
  const float* proj_b = (const float*)d_in[10];
  float* out = (float*)d_out;
  char* ws = (char*)d_ws;

  // workspace layout (bytes): requires ~134.8 MB
  unsigned short* comb = (unsigned short*)(ws + 0);          // 67,108,864
  float* bt = (float*)(ws + 67108864);                       // 30,752
  unsigned short* wqkv = (unsigned short*)(ws + 67141632);   // 393,216
  unsigned short* wproj = (unsigned short*)(ws + 67534848);  // 131,072
  unsigned short* Obuf = (unsigned short*)(ws + 67665920);   // 67,108,864 -> total 134,774,784

  k_cvt_w<<<dim3(1024), dim3(256), 0, stream>>>(qkv_w, proj_w, wqkv, wproj);
  k_cpb<<<dim3(961), dim3(64), 0, stream>>>(cpb_w1, cpb_b1, cpb_w2, bt);
  k_comb<<<dim3(16384), dim3(256), 0, stream>>>(mask, bt, comb);
  k_attn<<<dim3(4096), dim3(512), 0, stream>>>(x, q_bias, v_bias, logit_scale, wqkv, comb, Obuf);
  k_proj<<<dim3(2048), dim3(256), 0, stream>>>(Obuf, wproj, proj_b, out);
}

// Round 2
// 534.894 us; speedup vs baseline: 1.2922x; 1.2922x over previous
//
#include <hip/hip_runtime.h>
#include <hip/hip_bf16.h>
#include <hip/hip_fp16.h>

// SwinV2 window attention, MI355X/gfx950.
// Pipeline: cvt_w, cpb, rpb(1MB bias table), mskT(fp16 transpose),
//           2x [cvt_x(half) -> attn(half)], proj.
// attn: 1024 thr / 16 waves, wave = 16 q-rows; qkv GEMM staged via
// global_load_lds with pre-swizzled source; transposed MFMA orientation so
// norm epilogue is 4 shuffles/thread; full-row softmax in registers.

#define LOG100F 4.605170185988091f

typedef __attribute__((ext_vector_type(8))) __bf16 bf16x8;
typedef __attribute__((ext_vector_type(4))) float f32x4;
typedef __attribute__((ext_vector_type(8))) unsigned short u16x8;
typedef __attribute__((ext_vector_type(4))) unsigned short u16x4;

__device__ __forceinline__ unsigned short f2bfu(float f) {
  __hip_bfloat16 b = __float2bfloat16(f);
  return __builtin_bit_cast(unsigned short, b);
}
__device__ __forceinline__ unsigned short f2h(float f) {
  __half hv = __float2half(f);
  return __builtin_bit_cast(unsigned short, hv);
}
__device__ __forceinline__ float h2f(unsigned short b) {
  return __half2float(__builtin_bit_cast(__half, b));
}
__device__ __forceinline__ bf16x8 lds8(const unsigned short* p) {
  u16x8 v = *(const u16x8*)p;
  return __builtin_bit_cast(bf16x8, v);
}
__device__ __forceinline__ f32x4 mfma16(bf16x8 a, bf16x8 b, f32x4 c) {
  return __builtin_amdgcn_mfma_f32_16x16x32_bf16(a, b, c, 0, 0, 0);
}
// 16B-chunk XOR swizzle for [R][32]-u16 tiles: 2-way max on ds_read_b128
__device__ __forceinline__ int swc(int row, int kchunk) {
  return (kchunk ^ (row & 3) ^ ((row >> 2) & 3)) & 3;
}
__device__ __forceinline__ void gload_lds16(const void* g, void* l) {
  __builtin_amdgcn_global_load_lds(
      (const __attribute__((address_space(1))) void*)g,
      (__attribute__((address_space(3))) void*)l, 16, 0, 0);
}

// ---------------- weights -> bf16 ----------------
__global__ void k_cvt_w(const float* __restrict__ qkv_w, const float* __restrict__ proj_w,
                        unsigned short* __restrict__ wqkv, unsigned short* __restrict__ wproj) {
  const int t = blockIdx.x * 256 + threadIdx.x;
  if (t < 768 * 256) {
    wqkv[t] = f2bfu(qkv_w[t]);
  } else {
    const int t2 = t - 768 * 256;
    wproj[t2] = f2bfu(proj_w[t2]);
  }
}

// ---------------- x -> bf16 (half batch per call) ----------------
__global__ void k_cvt_x(const float* __restrict__ x, unsigned short* __restrict__ xb) {
  const int t = blockIdx.x * 256 + threadIdx.x;  // 8192 blocks -> 16,777,216 elems
  const float4 a = *(const float4*)(x + (size_t)t * 8);
  const float4 c = *(const float4*)(x + (size_t)t * 8 + 4);
  u16x8 ov;
  ov[0] = f2bfu(a.x); ov[1] = f2bfu(a.y); ov[2] = f2bfu(a.z); ov[3] = f2bfu(a.w);
  ov[4] = f2bfu(c.x); ov[5] = f2bfu(c.y); ov[6] = f2bfu(c.z); ov[7] = f2bfu(c.w);
  *(u16x8*)(xb + (size_t)t * 8) = ov;
}

// ---------------- CPB MLP -> bias_table[961][8] ----------------
__global__ void k_cpb(const float* __restrict__ w1, const float* __restrict__ b1,
                      const float* __restrict__ w2, float* __restrict__ bt) {
  const int row = blockIdx.x;    // 0..960
  const int lane = threadIdx.x;  // one wave
  const int i = row / 31, j = row % 31;
  float x0 = (i - 15) * (1.0f / 15.0f);
  float x1 = (j - 15) * (1.0f / 15.0f);
  float v0 = log2f(fmaf(8.0f, fabsf(x0), 1.0f)) * (1.0f / 3.0f); v0 = x0 < 0.0f ? -v0 : v0;
  float v1 = log2f(fmaf(8.0f, fabsf(x1), 1.0f)) * (1.0f / 3.0f); v1 = x1 < 0.0f ? -v1 : v1;
  float a[8] = {0.f, 0.f, 0.f, 0.f, 0.f, 0.f, 0.f, 0.f};
  for (int jj = lane; jj < 512; jj += 64) {
    float hv = fmaf(w1[2 * jj], v0, fmaf(w1[2 * jj + 1], v1, b1[jj]));
    hv = fmaxf(hv, 0.0f);
#pragma unroll
    for (int hh = 0; hh < 8; ++hh) a[hh] = fmaf(hv, w2[hh * 512 + jj], a[hh]);
  }
#pragma unroll
  for (int hh = 0; hh < 8; ++hh) {
#pragma unroll
    for (int mm = 1; mm < 64; mm <<= 1) a[hh] += __shfl_xor(a[hh], mm);
  }
  float outv = a[0];
#pragma unroll
  for (int hh = 1; hh < 8; ++hh)
    if (lane == hh) outv = a[hh];
  if (lane < 8) bt[row * 8 + lane] = outv;
}

// ---------------- rpb[h][m][n] = fp16(16*sigmoid(bt[idx(n,m)][h])) ----------------
__global__ void k_rpb(const float* __restrict__ bt, unsigned short* __restrict__ rpb) {
  const int t = blockIdx.x * 256 + threadIdx.x;  // 2048 blocks -> 524288
  const int n = t & 255, m = (t >> 8) & 255, h = t >> 16;
  const int ih = n >> 4, iw = n & 15, jh = m >> 4, jw = m & 15;
  const int idx = (ih - jh + 15) * 31 + (iw - jw + 15);
  const float bv = bt[idx * 8 + h];
  rpb[t] = f2h(16.0f / (1.0f + __expf(-bv)));
}

// ---------------- maskT[w][m][n] = fp16(mask[w][n][m]) ----------------
__global__ void k_mskT(const float* __restrict__ mask, unsigned short* __restrict__ maskT) {
  __shared__ float t[64][65];
  const int w = blockIdx.x >> 4, tile = blockIdx.x & 15;
  const int n0 = (tile >> 2) << 6, m0 = (tile & 3) << 6;
  const int tid = threadIdx.x;
  const int rr = tid >> 2, cb = (tid & 3) << 4;
#pragma unroll
  for (int e = 0; e < 16; e += 4) {
    const float4 v = *(const float4*)(mask + (size_t)(w * 256 + n0 + rr) * 256 + m0 + cb + e);
    t[rr][cb + e + 0] = v.x; t[rr][cb + e + 1] = v.y;
    t[rr][cb + e + 2] = v.z; t[rr][cb + e + 3] = v.w;
  }
  __syncthreads();
#pragma unroll
  for (int half = 0; half < 2; ++half) {
    u16x8 ov;
#pragma unroll
    for (int e = 0; e < 8; ++e) ov[e] = f2h(t[cb + half * 8 + e][rr]);
    *(u16x8*)(maskT + (size_t)(w * 256 + m0 + rr) * 256 + n0 + cb + half * 8) = ov;
  }
}

// ---------------- fused qkv + cosine attention, per (b,h) ----------------
__global__ __launch_bounds__(1024, 4) void k_attn(
    const unsigned short* __restrict__ xb, const float* __restrict__ q_bias,
    const float* __restrict__ v_bias, const float* __restrict__ logit_scale,
    const unsigned short* __restrict__ wqkv, const unsigned short* __restrict__ rpb,
    const unsigned short* __restrict__ maskT, unsigned short* __restrict__ Obuf,
    int b0) {
  __shared__ unsigned short lx[2][8192];  // x slice [256 tok][32 k], dbuf; reused as psw in PV
  __shared__ unsigned short lw[2][3072];  // W_h slice [96][32], dbuf
  __shared__ unsigned short lq[8192];     // q-hat [256 tok][32 d]
  __shared__ unsigned short lk[8192];     // k-hat [256 tok][32 d]
  __shared__ unsigned short lv[8192];     // v^T  [32 d][256 tok]

  const int bid = blockIdx.x;
  const int h = bid & 7, bl = bid >> 3;
  const int b = b0 + bl;
  const int w = b & 63;
  const int tid = threadIdx.x;
  const int lane = tid & 63, wid = tid >> 6;
  const int l16 = lane & 15, lg = lane >> 4;

  // ---- phase A: [96 wcols x 256 tok] = W_h . x^T, K=256 in 8 slices ----
  // staging: wave wid fills rows wid*16..+15 linearly; global source pre-swizzled
  const int srow = wid * 16 + (lane >> 2);
  const int pc = lane & 3;
  const int xlc = (pc ^ (srow & 3) ^ ((srow >> 2) & 3)) & 3;
  const unsigned short* xsrc0 = xb + (((bl << 8) + srow) << 8) + (xlc << 3);
  const unsigned short* wsrc0 =
      wqkv + ((((srow >> 5) << 8) + h * 32 + (srow & 31)) << 8) + (xlc << 3);

  f32x4 acc[6];
#pragma unroll
  for (int i = 0; i < 6; ++i) acc[i] = (f32x4){0.f, 0.f, 0.f, 0.f};

  gload_lds16(xsrc0, &lx[0][wid * 512]);
  if (wid < 6) gload_lds16(wsrc0, &lw[0][wid * 512]);
  __syncthreads();

  for (int kt = 0; kt < 8; ++kt) {
    const int cur = kt & 1;
    if (kt < 7) {
      const int k0 = (kt + 1) << 5;
      gload_lds16(xsrc0 + k0, &lx[cur ^ 1][wid * 512]);
      if (wid < 6) gload_lds16(wsrc0 + k0, &lw[cur ^ 1][wid * 512]);
    }
    const unsigned short* lxb = lx[cur];
    const unsigned short* lwb = lw[cur];
    const int n = wid * 16 + l16;
    const bf16x8 ax = lds8(lxb + n * 32 + (swc(n, lg) << 3));
#pragma unroll
    for (int mf = 0; mf < 6; ++mf) {
      const int m = mf * 16 + l16;
      const bf16x8 aw = lds8(lwb + m * 32 + (swc(m, lg) << 3));
      acc[mf] = mfma16(aw, ax, acc[mf]);
    }
    __syncthreads();
  }

  // ---- epilogue: lane owns token tok = wid*16+l16; d = mf*16+lg*4+r ----
  const float sl = __expf(fminf(logit_scale[h], LOG100F));
  const int tok = wid * 16 + l16;
  const float4 qb0 = *(const float4*)(q_bias + h * 32 + lg * 4);
  const float4 qb1 = *(const float4*)(q_bias + h * 32 + 16 + lg * 4);
  const float4 vb0 = *(const float4*)(v_bias + h * 32 + lg * 4);
  const float4 vb1 = *(const float4*)(v_bias + h * 32 + 16 + lg * 4);

  float q0[4], q1[4], k0v[4], k1v[4];
  float sq = 0.f, sk = 0.f;
#pragma unroll
  for (int r = 0; r < 4; ++r) {
    q0[r] = acc[0][r] + ((const float*)&qb0)[r];
    q1[r] = acc[1][r] + ((const float*)&qb1)[r];
    k0v[r] = acc[2][r];
    k1v[r] = acc[3][r];
    sq += q0[r] * q0[r] + q1[r] * q1[r];
    sk += k0v[r] * k0v[r] + k1v[r] * k1v[r];
  }
  sq += __shfl_xor(sq, 16); sq += __shfl_xor(sq, 32);
  sk += __shfl_xor(sk, 16); sk += __shfl_xor(sk, 32);
  const float rq = sl / fmaxf(sqrtf(sq), 1e-12f);
  const float rk = 1.f / fmaxf(sqrtf(sk), 1e-12f);
  {
    const int off0 = (lg & 1) * 4;
    u16x4 a, c;
#pragma unroll
    for (int r = 0; r < 4; ++r) { a[r] = f2bfu(q0[r] * rq); c[r] = f2bfu(k0v[r] * rk); }
    const int kc0 = lg >> 1;
    *(u16x4*)(lq + tok * 32 + (swc(tok, kc0) << 3) + off0) = a;
    *(u16x4*)(lk + tok * 32 + (swc(tok, kc0) << 3) + off0) = c;
    u16x4 a2, c2;
#pragma unroll
    for (int r = 0; r < 4; ++r) { a2[r] = f2bfu(q1[r] * rq); c2[r] = f2bfu(k1v[r] * rk); }
    const int kc1 = 2 + (lg >> 1);
    *(u16x4*)(lq + tok * 32 + (swc(tok, kc1) << 3) + off0) = a2;
    *(u16x4*)(lk + tok * 32 + (swc(tok, kc1) << 3) + off0) = c2;
  }
#pragma unroll
  for (int mf = 0; mf < 2; ++mf) {
    const float4 vb = mf ? vb1 : vb0;
#pragma unroll
    for (int r = 0; r < 4; ++r) {
      const int dd = mf * 16 + lg * 4 + r;
      const float vv = acc[4 + mf][r] + ((const float*)&vb)[r];
      lv[dd * 256 + ((((tok >> 3) ^ dd) & 31) << 3) + (tok & 7)] = f2bfu(vv);
    }
  }
  __syncthreads();

  // ---- phase B: S = q-hat . k-hat^T + bias, softmax, O = P.V ----
  const int qn = wid * 16 + l16;
  const bf16x8 aq = lds8(lq + qn * 32 + (swc(qn, lg) << 3));
  f32x4 s[16];
#pragma unroll
  for (int cf = 0; cf < 16; ++cf) {
    const int m = cf * 16 + l16;
    const bf16x8 bk = lds8(lk + m * 32 + (swc(m, lg) << 3));
    s[cf] = mfma16(aq, bk, (f32x4){0.f, 0.f, 0.f, 0.f});
  }
  // bias: rows n = wid*16+lg*4+r, col m = cf*16+l16
  const unsigned short* rbp = rpb + (h << 16);
  const unsigned short* mbp = maskT + (w << 16);
  const int nb4 = wid * 16 + lg * 4;
#pragma unroll
  for (int cf = 0; cf < 16; ++cf) {
    const int m = cf * 16 + l16;
    const u16x4 rv = *(const u16x4*)(rbp + m * 256 + nb4);
    const u16x4 mv = *(const u16x4*)(mbp + m * 256 + nb4);
#pragma unroll
    for (int r = 0; r < 4; ++r) s[cf][r] += h2f(rv[r]) + h2f(mv[r]);
  }
  float inv[4];
#pragma unroll
  for (int r = 0; r < 4; ++r) {
    float mx = s[0][r];
#pragma unroll
    for (int cf = 1; cf < 16; ++cf) mx = fmaxf(mx, s[cf][r]);
    mx = fmaxf(mx, __shfl_xor(mx, 1));
    mx = fmaxf(mx, __shfl_xor(mx, 2));
    mx = fmaxf(mx, __shfl_xor(mx, 4));
    mx = fmaxf(mx, __shfl_xor(mx, 8));
    float sm = 0.f;
#pragma unroll
    for (int cf = 0; cf < 16; ++cf) {
      const float p = __expf(s[cf][r] - mx);
      s[cf][r] = p;
      sm += p;
    }
    sm += __shfl_xor(sm, 1); sm += __shfl_xor(sm, 2);
    sm += __shfl_xor(sm, 4); sm += __shfl_xor(sm, 8);
    inv[r] = 1.f / sm;
  }
  // PV via per-wave LDS transpose of P (32-m chunks)
  f32x4 o0 = (f32x4){0.f, 0.f, 0.f, 0.f}, o1 = (f32x4){0.f, 0.f, 0.f, 0.f};
  unsigned short* psw = &lx[0][0] + wid * 512;
#pragma unroll
  for (int cc = 0; cc < 8; ++cc) {
#pragma unroll
    for (int q8 = 0; q8 < 2; ++q8) {
      const int cf = cc * 2 + q8;
      const int kch = q8 * 2 + (l16 >> 3);
      const int coff = l16 & 7;
#pragma unroll
      for (int r = 0; r < 4; ++r) {
        const int lr = lg * 4 + r;
        psw[lr * 32 + (swc(lr, kch) << 3) + coff] = f2bfu(s[cf][r]);
      }
    }
    asm volatile("s_waitcnt lgkmcnt(0)" ::: "memory");
    __builtin_amdgcn_sched_barrier(0);
    const bf16x8 pa = lds8(psw + l16 * 32 + (swc(l16, lg) << 3));
    const int d0 = l16;
    const bf16x8 bv0 = lds8(lv + d0 * 256 + ((((cc * 4 + lg) ^ d0) & 31) << 3));
    o0 = mfma16(pa, bv0, o0);
    const int d1 = 16 + l16;
    const bf16x8 bv1 = lds8(lv + d1 * 256 + ((((cc * 4 + lg) ^ d1) & 31) << 3));
    o1 = mfma16(pa, bv1, o1);
    __builtin_amdgcn_sched_barrier(0);
  }
#pragma unroll
  for (int r = 0; r < 4; ++r) {
    const int row = (b * 256 + wid * 16 + lg * 4 + r) << 8;
    Obuf[row + h * 32 + l16] = f2bfu(o0[r] * inv[r]);
    Obuf[row + h * 32 + 16 + l16] = f2bfu(o1[r] * inv[r]);
  }
}

// ---------------- out = O @ proj_w^T + proj_b (fp32) ----------------
__global__ __launch_bounds__(256, 2) void k_proj(
    const unsigned short* __restrict__ Obuf, const unsigned short* __restrict__ wproj,
    const float* __restrict__ proj_b, float* __restrict__ out) {
  __shared__ unsigned short la[128 * 32];
  __shared__ unsigned short lb[128 * 32];
  const int rb = blockIdx.x >> 1, cb = blockIdx.x & 1;
  const int tid = threadIdx.x, lane = tid & 63, wid = tid >> 6;
  const int wr = wid >> 1, wc = wid & 1;
  const int l16 = lane & 15, lg = lane >> 4;
  f32x4 acc[4][4];
#pragma unroll
  for (int i = 0; i < 4; ++i)
#pragma unroll
    for (int j = 0; j < 4; ++j) acc[i][j] = (f32x4){0.f, 0.f, 0.f, 0.f};
  for (int kt = 0; kt < 8; ++kt) {
    const int k0 = kt * 32;
#pragma unroll
    for (int it = 0; it < 2; ++it) {
      const int task = it * 256 + tid;
      const int row = task >> 2, c = task & 3;
      u16x8 va = *(const u16x8*)(Obuf + (rb * 128 + row) * 256 + k0 + c * 8);
      *(u16x8*)(la + row * 32 + ((c ^ (row & 3)) << 3)) = va;
      u16x8 vb = *(const u16x8*)(wproj + (cb * 128 + row) * 256 + k0 + c * 8);
      *(u16x8*)(lb + row * 32 + ((c ^ (row & 3)) << 3)) = vb;
    }
    __syncthreads();
    bf16x8 a[4];
#pragma unroll
    for (int af = 0; af < 4; ++af) {
      const int rr = wr * 64 + af * 16 + l16;
      a[af] = lds8(la + rr * 32 + ((lg ^ (rr & 3)) << 3));
    }
#pragma unroll
    for (int cf = 0; cf < 4; ++cf) {
      const int ccc = wc * 64 + cf * 16 + l16;
      bf16x8 bfr = lds8(lb + ccc * 32 + ((lg ^ (ccc & 3)) << 3));
#pragma unroll
      for (int af = 0; af < 4; ++af) acc[af][cf] = mfma16(a[af], bfr, acc[af][cf]);
    }
    __syncthreads();
  }
#pragma unroll
  for (int cf = 0; cf < 4; ++cf) {
    const int col = cb * 128 + wc * 64 + cf * 16 + l16;
    const float pb = proj_b[col];
#pragma unroll
    for (int af = 0; af < 4; ++af)
#pragma unroll
      for (int r = 0; r < 4; ++r) {
        const int row = rb * 128 + wr * 64 + af * 16 + lg * 4 + r;
        out[row * 256 + col] = acc[af][cf][r] + pb;
      }
  }
}

extern "C" void kernel_launch(void* const* d_in, const int* in_sizes, int n_in,
                              void* d_out, int out_size, void* d_ws, size_t ws_size,
                              hipStream_t stream) {
  (void)in_sizes; (void)n_in; (void)out_size; (void)ws_size;
  const float* x = (const float*)d_in[0];
  const float* mask = (const float*)d_in[1];
  const float* qkv_w = (const float*)d_in[2];
  const float* q_bias = (const float*)d_in[3];
  const float* v_bias = (const float*)d_in[4];
  const float* logit_scale = (const float*)d_in[5];
  const float* cpb_w1 = (const float*)d_in[6];
  const float* cpb_b1 = (const float*)d_in[7];
  const float* cpb_w2 = (const float*)d_in[8];
  const float* proj_w = (const float*)d_in[9];
  const float* proj_b = (const float*)d_in[10];
  float* out = (float*)d_out;
  char* ws = (char*)d_ws;

  // workspace layout (110.7 MB)
  unsigned short* xbb = (unsigned short*)(ws + 0);            // 33,554,432 (half batch)
  unsigned short* Obuf = (unsigned short*)(ws + 33554432);    // 67,108,864
  unsigned short* maskT = (unsigned short*)(ws + 100663296);  // 8,388,608
  unsigned short* rpbb = (unsigned short*)(ws + 109051904);   // 1,048,576
  float* bt = (float*)(ws + 110100480);                       // 30,752
  unsigned short* wqkv = (unsigned short*)(ws + 110131232);   // 393,216
  unsigned short* wproj = (unsigned short*)(ws + 110524448);  // 131,072

  k_cvt_w<<<dim3(1024), dim3(256), 0, stream>>>(qkv_w, proj_w, wqkv, wproj);
  k_cpb<<<dim3(961), dim3(64), 0, stream>>>(cpb_w1, cpb_b1, cpb_w2, bt);
  k_rpb<<<dim3(2048), dim3(256), 0, stream>>>(bt, rpbb);
  k_mskT<<<dim3(1024), dim3(256), 0, stream>>>(mask, maskT);

  k_cvt_x<<<dim3(8192), dim3(256), 0, stream>>>(x, xbb);
  k_attn<<<dim3(2048), dim3(1024), 0, stream>>>(xbb, q_bias, v_bias, logit_scale,
                                                wqkv, rpbb, maskT, Obuf, 0);
  k_cvt_x<<<dim3(8192), dim3(256), 0, stream>>>(x + 16777216, xbb);
  k_attn<<<dim3(2048), dim3(1024), 0, stream>>>(xbb, q_bias, v_bias, logit_scale,
                                                wqkv, rpbb, maskT, Obuf, 256);

  k_proj<<<dim3(2048), dim3(256), 0, stream>>>(Obuf, wproj, proj_b, out);
}

// Round 3
// 533.999 us; speedup vs baseline: 1.2944x; 1.0017x over previous
//
#include <hip/hip_runtime.h>
#include <hip/hip_bf16.h>
#include <hip/hip_fp16.h>

// SwinV2 window attention, MI355X/gfx950.
// Pipeline: cvt_w, cpb, rpb(1MB bias table), mskT(fp16 transpose),
//           2x [cvt_x(half) -> attn(half)], proj.
// attn: 1024 thr / 16 waves, wave = 16 q-rows; qkv GEMM staged via
// global_load_lds with pre-swizzled source; transposed MFMA orientation so
// norm epilogue is 4 shuffles/thread; full-row softmax in registers.

#define LOG100F 4.605170185988091f

typedef __attribute__((ext_vector_type(8))) __bf16 bf16x8;
typedef __attribute__((ext_vector_type(4))) float f32x4;
typedef __attribute__((ext_vector_type(8))) unsigned short u16x8;
typedef __attribute__((ext_vector_type(4))) unsigned short u16x4;

__device__ __forceinline__ unsigned short f2bfu(float f) {
  __hip_bfloat16 b = __float2bfloat16(f);
  return __builtin_bit_cast(unsigned short, b);
}
__device__ __forceinline__ unsigned short f2h(float f) {
  __half hv = __float2half(f);
  return __builtin_bit_cast(unsigned short, hv);
}
__device__ __forceinline__ float h2f(unsigned short b) {
  return __half2float(__builtin_bit_cast(__half, b));
}
__device__ __forceinline__ bf16x8 lds8(const unsigned short* p) {
  u16x8 v = *(const u16x8*)p;
  return __builtin_bit_cast(bf16x8, v);
}
__device__ __forceinline__ f32x4 mfma16(bf16x8 a, bf16x8 b, f32x4 c) {
  return __builtin_amdgcn_mfma_f32_16x16x32_bf16(a, b, c, 0, 0, 0);
}
// 16B-chunk XOR swizzle for [R][32]-u16 tiles: 2-way max on ds_read_b128
__device__ __forceinline__ int swc(int row, int kchunk) {
  return (kchunk ^ (row & 3) ^ ((row >> 2) & 3)) & 3;
}
__device__ __forceinline__ void gload_lds16(const void* g, void* l) {
  __builtin_amdgcn_global_load_lds(
      (const __attribute__((address_space(1))) void*)g,
      (__attribute__((address_space(3))) void*)l, 16, 0, 0);
}

// ---------------- weights -> bf16 ----------------
__global__ void k_cvt_w(const float* __restrict__ qkv_w, const float* __restrict__ proj_w,
                        unsigned short* __restrict__ wqkv, unsigned short* __restrict__ wproj) {
  const int t = blockIdx.x * 256 + threadIdx.x;
  if (t < 768 * 256) {
    wqkv[t] = f2bfu(qkv_w[t]);
  } else {
    const int t2 = t - 768 * 256;
    wproj[t2] = f2bfu(proj_w[t2]);
  }
}

// ---------------- x -> bf16 (half batch per call) ----------------
__global__ void k_cvt_x(const float* __restrict__ x, unsigned short* __restrict__ xb) {
  const int t = blockIdx.x * 256 + threadIdx.x;  // 8192 blocks -> 16,777,216 elems
  const float4 a = *(const float4*)(x + (size_t)t * 8);
  const float4 c = *(const float4*)(x + (size_t)t * 8 + 4);
  u16x8 ov;
  ov[0] = f2bfu(a.x); ov[1] = f2bfu(a.y); ov[2] = f2bfu(a.z); ov[3] = f2bfu(a.w);
  ov[4] = f2bfu(c.x); ov[5] = f2bfu(c.y); ov[6] = f2bfu(c.z); ov[7] = f2bfu(c.w);
  *(u16x8*)(xb + (size_t)t * 8) = ov;
}

// ---------------- CPB MLP -> bias_table[961][8] ----------------
__global__ void k_cpb(const float* __restrict__ w1, const float* __restrict__ b1,
                      const float* __restrict__ w2, float* __restrict__ bt) {
  const int row = blockIdx.x;    // 0..960
  const int lane = threadIdx.x;  // one wave
  const int i = row / 31, j = row % 31;
  float x0 = (i - 15) * (1.0f / 15.0f);
  float x1 = (j - 15) * (1.0f / 15.0f);
  float v0 = log2f(fmaf(8.0f, fabsf(x0), 1.0f)) * (1.0f / 3.0f); v0 = x0 < 0.0f ? -v0 : v0;
  float v1 = log2f(fmaf(8.0f, fabsf(x1), 1.0f)) * (1.0f / 3.0f); v1 = x1 < 0.0f ? -v1 : v1;
  float a[8] = {0.f, 0.f, 0.f, 0.f, 0.f, 0.f, 0.f, 0.f};
  for (int jj = lane; jj < 512; jj += 64) {
    float hv = fmaf(w1[2 * jj], v0, fmaf(w1[2 * jj + 1], v1, b1[jj]));
    hv = fmaxf(hv, 0.0f);
#pragma unroll
    for (int hh = 0; hh < 8; ++hh) a[hh] = fmaf(hv, w2[hh * 512 + jj], a[hh]);
  }
#pragma unroll
  for (int hh = 0; hh < 8; ++hh) {
#pragma unroll
    for (int mm = 1; mm < 64; mm <<= 1) a[hh] += __shfl_xor(a[hh], mm);
  }
  float outv = a[0];
#pragma unroll
  for (int hh = 1; hh < 8; ++hh)
    if (lane == hh) outv = a[hh];
  if (lane < 8) bt[row * 8 + lane] = outv;
}

// ---------------- rpb[h][m][n] = fp16(16*sigmoid(bt[idx(n,m)][h])) ----------------
__global__ void k_rpb(const float* __restrict__ bt, unsigned short* __restrict__ rpb) {
  const int t = blockIdx.x * 256 + threadIdx.x;  // 2048 blocks -> 524288
  const int n = t & 255, m = (t >> 8) & 255, h = t >> 16;
  const int ih = n >> 4, iw = n & 15, jh = m >> 4, jw = m & 15;
  const int idx = (ih - jh + 15) * 31 + (iw - jw + 15);
  const float bv = bt[idx * 8 + h];
  rpb[t] = f2h(16.0f / (1.0f + __expf(-bv)));
}

// ---------------- maskT[w][m][n] = fp16(mask[w][n][m]) ----------------
__global__ void k_mskT(const float* __restrict__ mask, unsigned short* __restrict__ maskT) {
  __shared__ float t[64][65];
  const int w = blockIdx.x >> 4, tile = blockIdx.x & 15;
  const int n0 = (tile >> 2) << 6, m0 = (tile & 3) << 6;
  const int tid = threadIdx.x;
  const int rr = tid >> 2, cb = (tid & 3) << 4;
#pragma unroll
  for (int e = 0; e < 16; e += 4) {
    const float4 v = *(const float4*)(mask + (size_t)(w * 256 + n0 + rr) * 256 + m0 + cb + e);
    t[rr][cb + e + 0] = v.x; t[rr][cb + e + 1] = v.y;
    t[rr][cb + e + 2] = v.z; t[rr][cb + e + 3] = v.w;
  }
  __syncthreads();
#pragma unroll
  for (int half = 0; half < 2; ++half) {
    u16x8 ov;
#pragma unroll
    for (int e = 0; e < 8; ++e) ov[e] = f2h(t[cb + half * 8 + e][rr]);
    *(u16x8*)(maskT + (size_t)(w * 256 + m0 + rr) * 256 + n0 + cb + half * 8) = ov;
  }
}

// ---------------- fused qkv + cosine attention, per (b,h) ----------------
__global__ __launch_bounds__(1024, 4) void k_attn(
    const unsigned short* __restrict__ xb, const float* __restrict__ q_bias,
    const float* __restrict__ v_bias, const float* __restrict__ logit_scale,
    const unsigned short* __restrict__ wqkv, const unsigned short* __restrict__ rpb,
    const unsigned short* __restrict__ maskT, unsigned short* __restrict__ Obuf,
    int b0) {
  __shared__ unsigned short lx[2][8192];  // x slice [256 tok][32 k], dbuf; reused as psw in PV
  __shared__ unsigned short lw[2][3072];  // W_h slice [96][32], dbuf
  __shared__ unsigned short lq[8192];     // q-hat [256 tok][32 d]
  __shared__ unsigned short lk[8192];     // k-hat [256 tok][32 d]
  __shared__ unsigned short lv[8192];     // v^T  [32 d][256 tok]

  const int bid = blockIdx.x;
  const int h = bid & 7, bl = bid >> 3;
  const int b = b0 + bl;
  const int w = b & 63;
  const int tid = threadIdx.x;
  const int lane = tid & 63, wid = tid >> 6;
  const int l16 = lane & 15, lg = lane >> 4;

  // ---- phase A: [96 wcols x 256 tok] = W_h . x^T, K=256 in 8 slices ----
  // staging: wave wid fills rows wid*16..+15 linearly; global source pre-swizzled
  const int srow = wid * 16 + (lane >> 2);
  const int pc = lane & 3;
  const int xlc = (pc ^ (srow & 3) ^ ((srow >> 2) & 3)) & 3;
  const unsigned short* xsrc0 = xb + (((bl << 8) + srow) << 8) + (xlc << 3);
  const unsigned short* wsrc0 =
      wqkv + ((((srow >> 5) << 8) + h * 32 + (srow & 31)) << 8) + (xlc << 3);

  f32x4 acc[6];
#pragma unroll
  for (int i = 0; i < 6; ++i) acc[i] = (f32x4){0.f, 0.f, 0.f, 0.f};

  gload_lds16(xsrc0, &lx[0][wid * 512]);
  if (wid < 6) gload_lds16(wsrc0, &lw[0][wid * 512]);
  __syncthreads();

  for (int kt = 0; kt < 8; ++kt) {
    const int cur = kt & 1;
    if (kt < 7) {
      const int k0 = (kt + 1) << 5;
      gload_lds16(xsrc0 + k0, &lx[cur ^ 1][wid * 512]);
      if (wid < 6) gload_lds16(wsrc0 + k0, &lw[cur ^ 1][wid * 512]);
    }
    const unsigned short* lxb = lx[cur];
    const unsigned short* lwb = lw[cur];
    const int n = wid * 16 + l16;
    const bf16x8 ax = lds8(lxb + n * 32 + (swc(n, lg) << 3));
#pragma unroll
    for (int mf = 0; mf < 6; ++mf) {
      const int m = mf * 16 + l16;
      const bf16x8 aw = lds8(lwb + m * 32 + (swc(m, lg) << 3));
      acc[mf] = mfma16(aw, ax, acc[mf]);
    }
    __syncthreads();
  }

  // ---- epilogue: lane owns token tok = wid*16+l16; d = mf*16+lg*4+r ----
  const float sl = __expf(fminf(logit_scale[h], LOG100F));
  const int tok = wid * 16 + l16;
  const float4 qb0 = *(const float4*)(q_bias + h * 32 + lg * 4);
  const float4 qb1 = *(const float4*)(q_bias + h * 32 + 16 + lg * 4);
  const float4 vb0 = *(const float4*)(v_bias + h * 32 + lg * 4);
  const float4 vb1 = *(const float4*)(v_bias + h * 32 + 16 + lg * 4);

  float q0[4], q1[4], k0v[4], k1v[4];
  float sq = 0.f, sk = 0.f;
#pragma unroll
  for (int r = 0; r < 4; ++r) {
    q0[r] = acc[0][r] + ((const float*)&qb0)[r];
    q1[r] = acc[1][r] + ((const float*)&qb1)[r];
    k0v[r] = acc[2][r];
    k1v[r] = acc[3][r];
    sq += q0[r] * q0[r] + q1[r] * q1[r];
    sk += k0v[r] * k0v[r] + k1v[r] * k1v[r];
  }
  sq += __shfl_xor(sq, 16); sq += __shfl_xor(sq, 32);
  sk += __shfl_xor(sk, 16); sk += __shfl_xor(sk, 32);
  const float rq = sl / fmaxf(sqrtf(sq), 1e-12f);
  const float rk = 1.f / fmaxf(sqrtf(sk), 1e-12f);
  {
    const int off0 = (lg & 1) * 4;
    u16x4 a, c;
#pragma unroll
    for (int r = 0; r < 4; ++r) { a[r] = f2bfu(q0[r] * rq); c[r] = f2bfu(k0v[r] * rk); }
    const int kc0 = lg >> 1;
    *(u16x4*)(lq + tok * 32 + (swc(tok, kc0) << 3) + off0) = a;
    *(u16x4*)(lk + tok * 32 + (swc(tok, kc0) << 3) + off0) = c;
    u16x4 a2, c2;
#pragma unroll
    for (int r = 0; r < 4; ++r) { a2[r] = f2bfu(q1[r] * rq); c2[r] = f2bfu(k1v[r] * rk); }
    const int kc1 = 2 + (lg >> 1);
    *(u16x4*)(lq + tok * 32 + (swc(tok, kc1) << 3) + off0) = a2;
    *(u16x4*)(lk + tok * 32 + (swc(tok, kc1) << 3) + off0) = c2;
  }
#pragma unroll
  for (int mf = 0; mf < 2; ++mf) {
    const float4 vb = mf ? vb1 : vb0;
#pragma unroll
    for (int r = 0; r < 4; ++r) {
      const int dd = mf * 16 + lg * 4 + r;
      const float vv = acc[4 + mf][r] + ((const float*)&vb)[r];
      lv[dd * 256 + ((((tok >> 3) ^ dd) & 31) << 3) + (tok & 7)] = f2bfu(vv);
    }
  }
  __syncthreads();

  // ---- phase B: S = q-hat . k-hat^T + bias, softmax, O = P.V ----
  const int qn = wid * 16 + l16;
  const bf16x8 aq = lds8(lq + qn * 32 + (swc(qn, lg) << 3));
  f32x4 s[16];
#pragma unroll
  for (int cf = 0; cf < 16; ++cf) {
    const int m = cf * 16 + l16;
    const bf16x8 bk = lds8(lk + m * 32 + (swc(m, lg) << 3));
    s[cf] = mfma16(aq, bk, (f32x4){0.f, 0.f, 0.f, 0.f});
  }
  // bias: rows n = wid*16+lg*4+r, col m = cf*16+l16
  const unsigned short* rbp = rpb + (h << 16);
  const unsigned short* mbp = maskT + (w << 16);
  const int nb4 = wid * 16 + lg * 4;
#pragma unroll
  for (int cf = 0; cf < 16; ++cf) {
    const int m = cf * 16 + l16;
    const u16x4 rv = *(const u16x4*)(rbp + m * 256 + nb4);
    const u16x4 mv = *(const u16x4*)(mbp + m * 256 + nb4);
#pragma unroll
    for (int r = 0; r < 4; ++r) s[cf][r] += h2f(rv[r]) + h2f(mv[r]);
  }
  float inv[4];
#pragma unroll
  for (int r = 0; r < 4; ++r) {
    float mx = s[0][r];
#pragma unroll
    for (int cf = 1; cf < 16; ++cf) mx = fmaxf(mx, s[cf][r]);
    mx = fmaxf(mx, __shfl_xor(mx, 1));
    mx = fmaxf(mx, __shfl_xor(mx, 2));
    mx = fmaxf(mx, __shfl_xor(mx, 4));
    mx = fmaxf(mx, __shfl_xor(mx, 8));
    float sm = 0.f;
#pragma unroll
    for (int cf = 0; cf < 16; ++cf) {
      const float p = __expf(s[cf][r] - mx);
      s[cf][r] = p;
      sm += p;
    }
    sm += __shfl_xor(sm, 1); sm += __shfl_xor(sm, 2);
    sm += __shfl_xor(sm, 4); sm += __shfl_xor(sm, 8);
    inv[r] = 1.f / sm;
  }
  // PV via per-wave LDS transpose of P (32-m chunks)
  f32x4 o0 = (f32x4){0.f, 0.f, 0.f, 0.f}, o1 = (f32x4){0.f, 0.f, 0.f, 0.f};
  unsigned short* psw = &lx[0][0] + wid * 512;
#pragma unroll
  for (int cc = 0; cc < 8; ++cc) {
#pragma unroll
    for (int q8 = 0; q8 < 2; ++q8) {
      const int cf = cc * 2 + q8;
      const int kch = q8 * 2 + (l16 >> 3);
      const int coff = l16 & 7;
#pragma unroll
      for (int r = 0; r < 4; ++r) {
        const int lr = lg * 4 + r;
        psw[lr * 32 + (swc(lr, kch) << 3) + coff] = f2bfu(s[cf][r]);
      }
    }
    asm volatile("s_waitcnt lgkmcnt(0)" ::: "memory");
    __builtin_amdgcn_sched_barrier(0);
    const bf16x8 pa = lds8(psw + l16 * 32 + (swc(l16, lg) << 3));
    const int d0 = l16;
    const bf16x8 bv0 = lds8(lv + d0 * 256 + ((((cc * 4 + lg) ^ d0) & 31) << 3));
    o0 = mfma16(pa, bv0, o0);
    const int d1 = 16 + l16;
    const bf16x8 bv1 = lds8(lv + d1 * 256 + ((((cc * 4 + lg) ^ d1) & 31) << 3));
    o1 = mfma16(pa, bv1, o1);
    __builtin_amdgcn_sched_barrier(0);
  }
#pragma unroll
  for (int r = 0; r < 4; ++r) {
    const int row = (b * 256 + wid * 16 + lg * 4 + r) << 8;
    Obuf[row + h * 32 + l16] = f2bfu(o0[r] * inv[r]);
    Obuf[row + h * 32 + 16 + l16] = f2bfu(o1[r] * inv[r]);
  }
}

// ---------------- out = O @ proj_w^T + proj_b (fp32) ----------------
__global__ __launch_bounds__(256, 2) void k_proj(
    const unsigned short* __restrict__ Obuf, const unsigned short* __restrict__ wproj,
    const float* __restrict__ proj_b, float* __restrict__ out) {
  __shared__ unsigned short la[128 * 32];
  __shared__ unsigned short lb[128 * 32];
  const int rb = blockIdx.x >> 1, cb = blockIdx.x & 1;
  const int tid = threadIdx.x, lane = tid & 63, wid = tid >> 6;
  const int wr = wid >> 1, wc = wid & 1;
  const int l16 = lane & 15, lg = lane >> 4;
  f32x4 acc[4][4];
#pragma unroll
  for (int i = 0; i < 4; ++i)
#pragma unroll
    for (int j = 0; j < 4; ++j) acc[i][j] = (f32x4){0.f, 0.f, 0.f, 0.f};
  for (int kt = 0; kt < 8; ++kt) {
    const int k0 = kt * 32;
#pragma unroll
    for (int it = 0; it < 2; ++it) {
      const int task = it * 256 + tid;
      const int row = task >> 2, c = task & 3;
      u16x8 va = *(const u16x8*)(Obuf + (rb * 128 + row) * 256 + k0 + c * 8);
      *(u16x8*)(la + row * 32 + ((c ^ (row & 3)) << 3)) = va;
      u16x8 vb = *(const u16x8*)(wproj + (cb * 128 + row) * 256 + k0 + c * 8);
      *(u16x8*)(lb + row * 32 + ((c ^ (row & 3)) << 3)) = vb;
    }
    __syncthreads();
    bf16x8 a[4];
#pragma unroll
    for (int af = 0; af < 4; ++af) {
      const int rr = wr * 64 + af * 16 + l16;
      a[af] = lds8(la + rr * 32 + ((lg ^ (rr & 3)) << 3));
    }
#pragma unroll
    for (int cf = 0; cf < 4; ++cf) {
      const int ccc = wc * 64 + cf * 16 + l16;
      bf16x8 bfr = lds8(lb + ccc * 32 + ((lg ^ (ccc & 3)) << 3));
#pragma unroll
      for (int af = 0; af < 4; ++af) acc[af][cf] = mfma16(a[af], bfr, acc[af][cf]);
    }
    __syncthreads();
  }
#pragma unroll
  for (int cf = 0; cf < 4; ++cf) {
    const int col = cb * 128 + wc * 64 + cf * 16 + l16;
    const float pb = proj_b[col];
#pragma unroll
    for (int af = 0; af < 4; ++af)
#pragma unroll
      for (int r = 0; r < 4; ++r) {
        const int row = rb * 128 + wr * 64 + af * 16 + lg * 4 + r;
        out[row * 256 + col] = acc[af][cf][r] + pb;
      }
  }
}

extern "C" void kernel_launch(void* const* d_in, const int* in_sizes, int n_in,
                              void* d_out, int out_size, void* d_ws, size_t ws_size,
                              hipStream_t stream) {
  (void)in_sizes; (void)n_in; (void)out_size; (void)ws_size;
  const float* x = (const float*)d_in[0];
  const float* mask = (const float*)d_in[1];
  const float* qkv_w = (const float*)d_in[2];
  const float* q_bias = (const float*)d_in[3];
  const float* v_bias = (const float*)d_in[4];
  const float* logit_scale = (const float*)d_in[5];
  const float* cpb_w1 = (const float*)d_in[6];
  const float* cpb_b1 = (const float*)d_in[7];
  const float* cpb_w2 = (const float*)d_in[8];
  const float* proj_w = (const float*)d_in[9];
  const float* proj_b = (const float*)d_in[10];
  float* out = (float*)d_out;
  char* ws = (char*)d_ws;

  // workspace layout (110.7 MB)
  unsigned short* xbb = (unsigned short*)(ws + 0);            // 33,554,432 (half batch)
  unsigned short* Obuf = (unsigned short*)(ws + 33554432);    // 67,108,864
  unsigned short* maskT = (unsigned short*)(ws + 100663296);  // 8,388,608
  unsigned short* rpbb = (unsigned short*)(ws + 109051904);   // 1,048,576
  float* bt = (float*)(ws + 110100480);                       // 30,752
  unsigned short* wqkv = (unsigned short*)(ws + 110131232);   // 393,216
  unsigned short* wproj = (unsigned short*)(ws + 110524448);  // 131,072

  k_cvt_w<<<dim3(1024), dim3(256), 0, stream>>>(qkv_w, proj_w, wqkv, wproj);
  k_cpb<<<dim3(961), dim3(64), 0, stream>>>(cpb_w1, cpb_b1, cpb_w2, bt);
  k_rpb<<<dim3(2048), dim3(256), 0, stream>>>(bt, rpbb);
  k_mskT<<<dim3(1024), dim3(256), 0, stream>>>(mask, maskT);

  k_cvt_x<<<dim3(8192), dim3(256), 0, stream>>>(x, xbb);
  k_attn<<<dim3(2048), dim3(1024), 0, stream>>>(xbb, q_bias, v_bias, logit_scale,
                                                wqkv, rpbb, maskT, Obuf, 0);
  k_cvt_x<<<dim3(8192), dim3(256), 0, stream>>>(x + 16777216, xbb);
  k_attn<<<dim3(2048), dim3(1024), 0, stream>>>(xbb, q_bias, v_bias, logit_scale,
                                                wqkv, rpbb, maskT, Obuf, 256);

  k_proj<<<dim3(2048), dim3(256), 0, stream>>>(Obuf, wproj, proj_b, out);
}

// Round 4
// 482.694 us; speedup vs baseline: 1.4320x; 1.1063x over previous
//
#include <hip/hip_runtime.h>
#include <hip/hip_bf16.h>
#include <hip/hip_fp16.h>

// SwinV2 window attention, MI355X/gfx950.
// Pipeline: cvt_w, cpb, rpb (1MB natural-layout bias, log2e-folded),
//           2x [cvt_x(half) -> attn(half)], proj.
// attn: 1024 thr / 16 waves, wave = 16 q-rows. Phase B uses SWAPPED QK^T
// (D cols = q) so each lane owns one q-row: softmax = 2+2 shuffles, bias
// reads natural-layout mask fp32 + rpb fp16, softmax in exp2 domain,
// P staged to per-wave LDS as u16x4 vectors. XCD-aware grid map keeps all
// 8 heads of a batch on one XCD (x[b] fetched once from HBM).

#define LOG100F 4.605170185988091f
#define LOG2EF 1.4426950408889634f

typedef __attribute__((ext_vector_type(8))) __bf16 bf16x8;
typedef __attribute__((ext_vector_type(4))) float f32x4;
typedef __attribute__((ext_vector_type(8))) unsigned short u16x8;
typedef __attribute__((ext_vector_type(4))) unsigned short u16x4;

__device__ __forceinline__ unsigned short f2bfu(float f) {
  __hip_bfloat16 b = __float2bfloat16(f);
  return __builtin_bit_cast(unsigned short, b);
}
__device__ __forceinline__ unsigned short f2h(float f) {
  __half hv = __float2half(f);
  return __builtin_bit_cast(unsigned short, hv);
}
__device__ __forceinline__ float h2f(unsigned short b) {
  return __half2float(__builtin_bit_cast(__half, b));
}
__device__ __forceinline__ bf16x8 lds8(const unsigned short* p) {
  u16x8 v = *(const u16x8*)p;
  return __builtin_bit_cast(bf16x8, v);
}
__device__ __forceinline__ f32x4 mfma16(bf16x8 a, bf16x8 b, f32x4 c) {
  return __builtin_amdgcn_mfma_f32_16x16x32_bf16(a, b, c, 0, 0, 0);
}
__device__ __forceinline__ float fexp2(float x) {
#if __has_builtin(__builtin_amdgcn_exp2f)
  return __builtin_amdgcn_exp2f(x);
#else
  return exp2f(x);
#endif
}
// 16B-chunk XOR swizzle for [R][32]-u16 tiles: <=2-way on ds_read_b128
__device__ __forceinline__ int swc(int row, int kchunk) {
  return (kchunk ^ (row & 3) ^ ((row >> 2) & 3)) & 3;
}
__device__ __forceinline__ void gload_lds16(const void* g, void* l) {
  __builtin_amdgcn_global_load_lds(
      (const __attribute__((address_space(1))) void*)g,
      (__attribute__((address_space(3))) void*)l, 16, 0, 0);
}

// ---------------- weights -> bf16 ----------------
__global__ void k_cvt_w(const float* __restrict__ qkv_w, const float* __restrict__ proj_w,
                        unsigned short* __restrict__ wqkv, unsigned short* __restrict__ wproj) {
  const int t = blockIdx.x * 256 + threadIdx.x;
  if (t < 768 * 256) {
    wqkv[t] = f2bfu(qkv_w[t]);
  } else {
    const int t2 = t - 768 * 256;
    wproj[t2] = f2bfu(proj_w[t2]);
  }
}

// ---------------- x -> bf16 (half batch per call) ----------------
__global__ void k_cvt_x(const float* __restrict__ x, unsigned short* __restrict__ xb) {
  const int t = blockIdx.x * 256 + threadIdx.x;
  const float4 a = *(const float4*)(x + (size_t)t * 8);
  const float4 c = *(const float4*)(x + (size_t)t * 8 + 4);
  u16x8 ov;
  ov[0] = f2bfu(a.x); ov[1] = f2bfu(a.y); ov[2] = f2bfu(a.z); ov[3] = f2bfu(a.w);
  ov[4] = f2bfu(c.x); ov[5] = f2bfu(c.y); ov[6] = f2bfu(c.z); ov[7] = f2bfu(c.w);
  *(u16x8*)(xb + (size_t)t * 8) = ov;
}

// ---------------- CPB MLP -> bias_table[961][8] ----------------
__global__ void k_cpb(const float* __restrict__ w1, const float* __restrict__ b1,
                      const float* __restrict__ w2, float* __restrict__ bt) {
  const int row = blockIdx.x;
  const int lane = threadIdx.x;
  const int i = row / 31, j = row % 31;
  float x0 = (i - 15) * (1.0f / 15.0f);
  float x1 = (j - 15) * (1.0f / 15.0f);
  float v0 = log2f(fmaf(8.0f, fabsf(x0), 1.0f)) * (1.0f / 3.0f); v0 = x0 < 0.0f ? -v0 : v0;
  float v1 = log2f(fmaf(8.0f, fabsf(x1), 1.0f)) * (1.0f / 3.0f); v1 = x1 < 0.0f ? -v1 : v1;
  float a[8] = {0.f, 0.f, 0.f, 0.f, 0.f, 0.f, 0.f, 0.f};
  for (int jj = lane; jj < 512; jj += 64) {
    float hv = fmaf(w1[2 * jj], v0, fmaf(w1[2 * jj + 1], v1, b1[jj]));
    hv = fmaxf(hv, 0.0f);
#pragma unroll
    for (int hh = 0; hh < 8; ++hh) a[hh] = fmaf(hv, w2[hh * 512 + jj], a[hh]);
  }
#pragma unroll
  for (int hh = 0; hh < 8; ++hh) {
#pragma unroll
    for (int mm = 1; mm < 64; mm <<= 1) a[hh] += __shfl_xor(a[hh], mm);
  }
  float outv = a[0];
#pragma unroll
  for (int hh = 1; hh < 8; ++hh)
    if (lane == hh) outv = a[hh];
  if (lane < 8) bt[row * 8 + lane] = outv;
}

// ------- rpbn[h][n][m] = fp16(log2e * 16*sigmoid(bt[idx(n,m)][h])) -------
__global__ void k_rpb(const float* __restrict__ bt, unsigned short* __restrict__ rpbn) {
  const int t = blockIdx.x * 256 + threadIdx.x;  // 2048 blocks -> 524288
  const int m = t & 255, n = (t >> 8) & 255, h = t >> 16;
  const int ih = n >> 4, iw = n & 15, jh = m >> 4, jw = m & 15;
  const int idx = (ih - jh + 15) * 31 + (iw - jw + 15);
  const float bv = bt[idx * 8 + h];
  rpbn[t] = f2h(LOG2EF * 16.0f / (1.0f + __expf(-bv)));
}

// ---------------- fused qkv + cosine attention, per (b,h) ----------------
__global__ __launch_bounds__(1024, 4) void k_attn(
    const unsigned short* __restrict__ xb, const float* __restrict__ q_bias,
    const float* __restrict__ v_bias, const float* __restrict__ logit_scale,
    const unsigned short* __restrict__ wqkv, const unsigned short* __restrict__ rpbn,
    const float* __restrict__ mask, unsigned short* __restrict__ Obuf, int b0) {
  __shared__ unsigned short lx[2][8192];  // x slice [256 tok][32 k], dbuf; reused as psw in PV
  __shared__ unsigned short lw[2][3072];  // W_h slice [96][32], dbuf
  __shared__ unsigned short lq[8192];     // q-hat [256 tok][32 d]
  __shared__ unsigned short lk[8192];     // k-hat [256 tok][32 d]
  __shared__ unsigned short lv[8192];     // v^T  [32 d][256 tok]

  // XCD-aware map: bid = g*64 + h*8 + x (x = XCD = bid%8); bl = g*8 + x.
  // All 8 heads of one batch are adjacent-in-dispatch on the same XCD.
  const int bid = blockIdx.x;
  const int xcd = bid & 7, h = (bid >> 3) & 7, g = bid >> 6;
  const int bl = g * 8 + xcd;
  const int b = b0 + bl;
  const int w = b & 63;
  const int tid = threadIdx.x;
  const int lane = tid & 63, wid = tid >> 6;
  const int l16 = lane & 15, lg = lane >> 4;

  // ---- phase A: [96 wcols x 256 tok] = W_h . x^T, K=256 in 8 slices ----
  const int srow = wid * 16 + (lane >> 2);
  const int pc = lane & 3;
  const int xlc = (pc ^ (srow & 3) ^ ((srow >> 2) & 3)) & 3;
  const unsigned short* xsrc0 = xb + (((bl << 8) + srow) << 8) + (xlc << 3);
  const unsigned short* wsrc0 =
      wqkv + ((((srow >> 5) << 8) + h * 32 + (srow & 31)) << 8) + (xlc << 3);

  f32x4 acc[6];
#pragma unroll
  for (int i = 0; i < 6; ++i) acc[i] = (f32x4){0.f, 0.f, 0.f, 0.f};

  gload_lds16(xsrc0, &lx[0][wid * 512]);
  if (wid < 6) gload_lds16(wsrc0, &lw[0][wid * 512]);
  __syncthreads();

  for (int kt = 0; kt < 8; ++kt) {
    const int cur = kt & 1;
    if (kt < 7) {
      const int k0 = (kt + 1) << 5;
      gload_lds16(xsrc0 + k0, &lx[cur ^ 1][wid * 512]);
      if (wid < 6) gload_lds16(wsrc0 + k0, &lw[cur ^ 1][wid * 512]);
    }
    const unsigned short* lxb = lx[cur];
    const unsigned short* lwb = lw[cur];
    const int n = wid * 16 + l16;
    const bf16x8 ax = lds8(lxb + n * 32 + (swc(n, lg) << 3));
#pragma unroll
    for (int mf = 0; mf < 6; ++mf) {
      const int m = mf * 16 + l16;
      const bf16x8 aw = lds8(lwb + m * 32 + (swc(m, lg) << 3));
      acc[mf] = mfma16(aw, ax, acc[mf]);
    }
    __syncthreads();
  }

  // ---- epilogue: lane owns token tok = wid*16+l16; d = mf*16+lg*4+r ----
  // fold log2e into the logit scale -> S lands in exp2 domain
  const float sl = __expf(fminf(logit_scale[h], LOG100F)) * LOG2EF;
  const int tok = wid * 16 + l16;
  const float4 qb0 = *(const float4*)(q_bias + h * 32 + lg * 4);
  const float4 qb1 = *(const float4*)(q_bias + h * 32 + 16 + lg * 4);
  const float4 vb0 = *(const float4*)(v_bias + h * 32 + lg * 4);
  const float4 vb1 = *(const float4*)(v_bias + h * 32 + 16 + lg * 4);

  float q0[4], q1[4], k0v[4], k1v[4];
  float sq = 0.f, sk = 0.f;
#pragma unroll
  for (int r = 0; r < 4; ++r) {
    q0[r] = acc[0][r] + ((const float*)&qb0)[r];
    q1[r] = acc[1][r] + ((const float*)&qb1)[r];
    k0v[r] = acc[2][r];
    k1v[r] = acc[3][r];
    sq += q0[r] * q0[r] + q1[r] * q1[r];
    sk += k0v[r] * k0v[r] + k1v[r] * k1v[r];
  }
  sq += __shfl_xor(sq, 16); sq += __shfl_xor(sq, 32);
  sk += __shfl_xor(sk, 16); sk += __shfl_xor(sk, 32);
  const float rq = sl / fmaxf(sqrtf(sq), 1e-12f);
  const float rk = 1.f / fmaxf(sqrtf(sk), 1e-12f);
  {
    const int off0 = (lg & 1) * 4;
    u16x4 a, c;
#pragma unroll
    for (int r = 0; r < 4; ++r) { a[r] = f2bfu(q0[r] * rq); c[r] = f2bfu(k0v[r] * rk); }
    const int kc0 = lg >> 1;
    *(u16x4*)(lq + tok * 32 + (swc(tok, kc0) << 3) + off0) = a;
    *(u16x4*)(lk + tok * 32 + (swc(tok, kc0) << 3) + off0) = c;
    u16x4 a2, c2;
#pragma unroll
    for (int r = 0; r < 4; ++r) { a2[r] = f2bfu(q1[r] * rq); c2[r] = f2bfu(k1v[r] * rk); }
    const int kc1 = 2 + (lg >> 1);
    *(u16x4*)(lq + tok * 32 + (swc(tok, kc1) << 3) + off0) = a2;
    *(u16x4*)(lk + tok * 32 + (swc(tok, kc1) << 3) + off0) = c2;
  }
#pragma unroll
  for (int mf = 0; mf < 2; ++mf) {
    const float4 vb = mf ? vb1 : vb0;
#pragma unroll
    for (int r = 0; r < 4; ++r) {
      const int dd = mf * 16 + lg * 4 + r;
      const float vv = acc[4 + mf][r] + ((const float*)&vb)[r];
      lv[dd * 256 + ((((tok >> 3) ^ dd) & 31) << 3) + (tok & 7)] = f2bfu(vv);
    }
  }
  __syncthreads();

  // ---- phase B (swapped): s[cf] = mfma(k-hat, q-hat) -> lane owns q = l16 ----
  // D[row = m_local = lg*4+r][col = q = l16]; m = cf*16 + lg*4 + r
  const int q = wid * 16 + l16;
  const bf16x8 aq = lds8(lq + q * 32 + (swc(q, lg) << 3));
  f32x4 s[16];
#pragma unroll
  for (int cf = 0; cf < 16; ++cf) {
    const int m = cf * 16 + l16;
    const bf16x8 bk = lds8(lk + m * 32 + (swc(m, lg) << 3));
    s[cf] = mfma16(bk, aq, (f32x4){0.f, 0.f, 0.f, 0.f});
  }
  // bias: natural layout, row q fixed per lane, m = cf*16+lg*4+r consecutive
  const unsigned short* rbp = rpbn + (h << 16) + (q << 8) + lg * 4;
  const float* mbp = mask + (w << 16) + (q << 8) + lg * 4;
#pragma unroll
  for (int cf = 0; cf < 16; ++cf) {
    const u16x4 rv = *(const u16x4*)(rbp + cf * 16);
    const float4 mv = *(const float4*)(mbp + cf * 16);
    s[cf][0] = fmaf(mv.x, LOG2EF, s[cf][0] + h2f(rv[0]));
    s[cf][1] = fmaf(mv.y, LOG2EF, s[cf][1] + h2f(rv[1]));
    s[cf][2] = fmaf(mv.z, LOG2EF, s[cf][2] + h2f(rv[2]));
    s[cf][3] = fmaf(mv.w, LOG2EF, s[cf][3] + h2f(rv[3]));
  }
  // softmax over m: 64 in-lane values + lg-reduce (xor 16, 32); exp2 domain
  float mx = s[0][0];
#pragma unroll
  for (int cf = 0; cf < 16; ++cf) {
#pragma unroll
    for (int r = 0; r < 4; ++r) mx = fmaxf(mx, s[cf][r]);
  }
  mx = fmaxf(mx, __shfl_xor(mx, 16));
  mx = fmaxf(mx, __shfl_xor(mx, 32));
  float sm = 0.f;
#pragma unroll
  for (int cf = 0; cf < 16; ++cf) {
#pragma unroll
    for (int r = 0; r < 4; ++r) {
      const float p = fexp2(s[cf][r] - mx);
      s[cf][r] = p;
      sm += p;
    }
  }
  sm += __shfl_xor(sm, 16);
  sm += __shfl_xor(sm, 32);
  const float inv = 1.f / sm;  // per-lane: normalizer for q-row l16 (deferred)

  // PV: lane holds P[m][q=l16]; stage into psw rows = q_local = l16 (u16x4)
  f32x4 o0 = (f32x4){0.f, 0.f, 0.f, 0.f}, o1 = (f32x4){0.f, 0.f, 0.f, 0.f};
  unsigned short* psw = &lx[0][0] + wid * 512;
#pragma unroll
  for (int cc = 0; cc < 8; ++cc) {
#pragma unroll
    for (int q8 = 0; q8 < 2; ++q8) {
      const int cf = cc * 2 + q8;
      u16x4 pk;
#pragma unroll
      for (int r = 0; r < 4; ++r) pk[r] = f2bfu(s[cf][r]);
      const int ch = q8 * 2 + (lg >> 1);
      *(u16x4*)(psw + l16 * 32 + (swc(l16, ch) << 3) + (lg & 1) * 4) = pk;
    }
    asm volatile("s_waitcnt lgkmcnt(0)" ::: "memory");
    __builtin_amdgcn_sched_barrier(0);
    const bf16x8 pa = lds8(psw + l16 * 32 + (swc(l16, lg) << 3));
    const int d0 = l16;
    const bf16x8 bv0 = lds8(lv + d0 * 256 + ((((cc * 4 + lg) ^ d0) & 31) << 3));
    o0 = mfma16(pa, bv0, o0);
    const int d1 = 16 + l16;
    const bf16x8 bv1 = lds8(lv + d1 * 256 + ((((cc * 4 + lg) ^ d1) & 31) << 3));
    o1 = mfma16(pa, bv1, o1);
    __builtin_amdgcn_sched_barrier(0);
  }
  // O rows = q_local = lg*4+r; fetch that row's normalizer from lane lg*4+r
#pragma unroll
  for (int r = 0; r < 4; ++r) {
    const float iv = __shfl(inv, lg * 4 + r);
    const int row = (b * 256 + wid * 16 + lg * 4 + r) << 8;
    Obuf[row + h * 32 + l16] = f2bfu(o0[r] * iv);
    Obuf[row + h * 32 + 16 + l16] = f2bfu(o1[r] * iv);
  }
}

// ---------------- out = O @ proj_w^T + proj_b (fp32) ----------------
__global__ __launch_bounds__(256, 2) void k_proj(
    const unsigned short* __restrict__ Obuf, const unsigned short* __restrict__ wproj,
    const float* __restrict__ proj_b, float* __restrict__ out) {
  __shared__ unsigned short la[128 * 32];
  __shared__ unsigned short lb[128 * 32];
  const int rb = blockIdx.x >> 1, cb = blockIdx.x & 1;
  const int tid = threadIdx.x, lane = tid & 63, wid = tid >> 6;
  const int wr = wid >> 1, wc = wid & 1;
  const int l16 = lane & 15, lg = lane >> 4;
  f32x4 acc[4][4];
#pragma unroll
  for (int i = 0; i < 4; ++i)
#pragma unroll
    for (int j = 0; j < 4; ++j) acc[i][j] = (f32x4){0.f, 0.f, 0.f, 0.f};
  for (int kt = 0; kt < 8; ++kt) {
    const int k0 = kt * 32;
#pragma unroll
    for (int it = 0; it < 2; ++it) {
      const int task = it * 256 + tid;
      const int row = task >> 2, c = task & 3;
      u16x8 va = *(const u16x8*)(Obuf + (rb * 128 + row) * 256 + k0 + c * 8);
      *(u16x8*)(la + row * 32 + ((c ^ (row & 3)) << 3)) = va;
      u16x8 vb = *(const u16x8*)(wproj + (cb * 128 + row) * 256 + k0 + c * 8);
      *(u16x8*)(lb + row * 32 + ((c ^ (row & 3)) << 3)) = vb;
    }
    __syncthreads();
    bf16x8 a[4];
#pragma unroll
    for (int af = 0; af < 4; ++af) {
      const int rr = wr * 64 + af * 16 + l16;
      a[af] = lds8(la + rr * 32 + ((lg ^ (rr & 3)) << 3));
    }
#pragma unroll
    for (int cf = 0; cf < 4; ++cf) {
      const int ccc = wc * 64 + cf * 16 + l16;
      bf16x8 bfr = lds8(lb + ccc * 32 + ((lg ^ (ccc & 3)) << 3));
#pragma unroll
      for (int af = 0; af < 4; ++af) acc[af][cf] = mfma16(a[af], bfr, acc[af][cf]);
    }
    __syncthreads();
  }
#pragma unroll
  for (int cf = 0; cf < 4; ++cf) {
    const int col = cb * 128 + wc * 64 + cf * 16 + l16;
    const float pb = proj_b[col];
#pragma unroll
    for (int af = 0; af < 4; ++af)
#pragma unroll
      for (int r = 0; r < 4; ++r) {
        const int row = rb * 128 + wr * 64 + af * 16 + lg * 4 + r;
        out[row * 256 + col] = acc[af][cf][r] + pb;
      }
  }
}

extern "C" void kernel_launch(void* const* d_in, const int* in_sizes, int n_in,
                              void* d_out, int out_size, void* d_ws, size_t ws_size,
                              hipStream_t stream) {
  (void)in_sizes; (void)n_in; (void)out_size; (void)ws_size;
  const float* x = (const float*)d_in[0];
  const float* mask = (const float*)d_in[1];
  const float* qkv_w = (const float*)d_in[2];
  const float* q_bias = (const float*)d_in[3];
  const float* v_bias = (const float*)d_in[4];
  const float* logit_scale = (const float*)d_in[5];
  const float* cpb_w1 = (const float*)d_in[6];
  const float* cpb_b1 = (const float*)d_in[7];
  const float* cpb_w2 = (const float*)d_in[8];
  const float* proj_w = (const float*)d_in[9];
  const float* proj_b = (const float*)d_in[10];
  float* out = (float*)d_out;
  char* ws = (char*)d_ws;

  // workspace layout (~102.3 MB)
  unsigned short* xbb = (unsigned short*)(ws + 0);            // 33,554,432 (half batch)
  unsigned short* Obuf = (unsigned short*)(ws + 33554432);    // 67,108,864
  unsigned short* rpbn = (unsigned short*)(ws + 100663296);   // 1,048,576
  float* bt = (float*)(ws + 101711872);                       // 30,752
  unsigned short* wqkv = (unsigned short*)(ws + 101742624);   // 393,216
  unsigned short* wproj = (unsigned short*)(ws + 102135840);  // 131,072

  k_cvt_w<<<dim3(1024), dim3(256), 0, stream>>>(qkv_w, proj_w, wqkv, wproj);
  k_cpb<<<dim3(961), dim3(64), 0, stream>>>(cpb_w1, cpb_b1, cpb_w2, bt);
  k_rpb<<<dim3(2048), dim3(256), 0, stream>>>(bt, rpbn);

  k_cvt_x<<<dim3(8192), dim3(256), 0, stream>>>(x, xbb);
  k_attn<<<dim3(2048), dim3(1024), 0, stream>>>(xbb, q_bias, v_bias, logit_scale,
                                                wqkv, rpbn, mask, Obuf, 0);
  k_cvt_x<<<dim3(8192), dim3(256), 0, stream>>>(x + 16777216, xbb);
  k_attn<<<dim3(2048), dim3(1024), 0, stream>>>(xbb, q_bias, v_bias, logit_scale,
                                                wqkv, rpbn, mask, Obuf, 256);

  k_proj<<<dim3(2048), dim3(256), 0, stream>>>(Obuf, wproj, proj_b, out);
}